// Round 13
// baseline (573.637 us; speedup 1.0000x reference)
//
#include <hip/hip_runtime.h>

#define B_ 4
#define S_ 2048
#define E_ 1024

typedef __attribute__((ext_vector_type(8))) short short8;
typedef __attribute__((ext_vector_type(4))) float f32x4;

__device__ __forceinline__ unsigned short f2bu(float f) {
  unsigned u = __builtin_bit_cast(unsigned, f);
  u = (u + 0x7FFFu + ((u >> 16) & 1u)) >> 16;
  return (unsigned short)u;
}

__device__ __forceinline__ void gload_lds16(const void* g, void* l) {
  __builtin_amdgcn_global_load_lds(
      (const __attribute__((address_space(1))) void*)g,
      (__attribute__((address_space(3))) void*)l, 16, 0, 0);
}

// ---------------- fp32 -> bf16 converts ----------------
__global__ __launch_bounds__(256) void cvt_f32_bf16(
    const float* __restrict__ in, unsigned short* __restrict__ out, int n) {
  int i = blockIdx.x * 256 + threadIdx.x;
  if (i * 4 >= n) return;
  float4 v = ((const float4*)in)[i];
  ushort4 o;
  o.x = f2bu(v.x); o.y = f2bu(v.y); o.z = f2bu(v.z); o.w = f2bu(v.w);
  ((ushort4*)out)[i] = o;
}

__global__ __launch_bounds__(256) void cvt_w3(
    const float* __restrict__ w0, const float* __restrict__ w1,
    const float* __restrict__ w2, unsigned short* __restrict__ out, int n) {
  int z = blockIdx.z;
  const float* in = (z == 0) ? w0 : (z == 1) ? w1 : w2;
  int i = blockIdx.x * 256 + threadIdx.x;
  if (i * 4 >= n) return;
  float4 v = ((const float4*)in)[i];
  ushort4 o;
  o.x = f2bu(v.x); o.y = f2bu(v.y); o.z = f2bu(v.z); o.w = f2bu(v.w);
  ((ushort4*)(out + (long)z * n))[i] = o;
}

// ---------------- zero the softmax denominator buffer ----------------
__global__ __launch_bounds__(256) void zden(float* __restrict__ d) {
  ((float4*)d)[blockIdx.x * 256 + threadIdx.x] = float4{0.f, 0.f, 0.f, 0.f};
}

// ================= k_qkv: m97 2-phase, BM=256 x BN=128, 8 waves ============
// C[8192][3072] = xb * [Wq;Wk;Wv]^T + bias.  768 blocks = EXACTLY one
// residency round at 3 blocks/CU (was 1536 blocks = 2 rounds at the 128^2
// tile).  Per-wave per-K-step work identical to the proven m97 body
// (32 MFMA, 16 ds_read_b128); per-CU resident waves 12 -> 24 into the
// 72%-idle MFMA pipe.  LDS 48KB x 3 = 144KB <= 160KB.
__global__ __launch_bounds__(512, 6) void k_qkv(
    const unsigned short* __restrict__ A, const unsigned short* __restrict__ W,
    const float* __restrict__ bq, const float* __restrict__ bk,
    const float* __restrict__ bv,
    unsigned short* __restrict__ Qo, unsigned short* __restrict__ Ko,
    unsigned short* __restrict__ Vt) {
  __shared__ unsigned short lA[256 * 64];  // 32KB
  __shared__ unsigned short lB[128 * 64];  // 16KB
  int bid = blockIdx.y * 24 + blockIdx.x;
  int nb = (bid & 7) * 96 + (bid >> 3);  // XCD-chunked, 768 = 8*96 bijective
  int bm = nb / 24, bn = nb % 24;        // bm 0..31, bn 0..23

  int tid = threadIdx.x;
  int l = tid & 63, w = tid >> 6;        // 8 waves
  int wm = w >> 1, wn = w & 1;           // 4 x 2 wave grid, tile 64x64

  const unsigned short* Ab = A + (long)bm * 256 * E_;
  const unsigned short* Bb = W + (long)bn * 128 * E_;

  // staging: A 32 chunks of 1KB (4/wave), B 16 chunks (2/wave)
  int srow = l >> 3, schunk = (l & 7) * 8;
  const unsigned short* ga[4];
  unsigned short* lad[4];
#pragma unroll
  for (int i = 0; i < 4; i++) {
    int seg = i * 8 + w;                 // 0..31
    ga[i] = Ab + (long)(seg * 8 + srow) * E_ + schunk;
    lad[i] = &lA[seg * 512];
  }
  const unsigned short* gb[2];
  unsigned short* lbd[2];
#pragma unroll
  for (int i = 0; i < 2; i++) {
    int seg = i * 8 + w;                 // 0..15
    gb[i] = Bb + (long)(seg * 8 + srow) * E_ + schunk;
    lbd[i] = &lB[seg * 512];
  }

  int aoff[4], boff[4];
#pragma unroll
  for (int i = 0; i < 4; i++) {
    aoff[i] = (wm * 64 + i * 16 + (l & 15)) * 64 + (l >> 4) * 8;
    boff[i] = (wn * 64 + i * 16 + (l & 15)) * 64 + (l >> 4) * 8;
  }

  f32x4 acc[4][4] = {};

  for (int k0 = 0; k0 < E_; k0 += 64) {
    __syncthreads();
#pragma unroll
    for (int i = 0; i < 4; i++) { gload_lds16(ga[i], lad[i]); ga[i] += 64; }
#pragma unroll
    for (int i = 0; i < 2; i++) { gload_lds16(gb[i], lbd[i]); gb[i] += 64; }
    __syncthreads();
#pragma unroll
    for (int kk = 0; kk < 2; kk++) {
      short8 af[4], bf[4];
#pragma unroll
      for (int i = 0; i < 4; i++) af[i] = *(const short8*)&lA[aoff[i] + kk * 32];
#pragma unroll
      for (int j = 0; j < 4; j++) bf[j] = *(const short8*)&lB[boff[j] + kk * 32];
#pragma unroll
      for (int i = 0; i < 4; i++)
#pragma unroll
        for (int j = 0; j < 4; j++)
          acc[i][j] = __builtin_amdgcn_mfma_f32_16x16x32_bf16(af[i], bf[j], acc[i][j], 0, 0, 0);
    }
  }

  // epilogue: D col = lane&15, row = (lane>>4)*4 + t   [m89-verified]
  int rh = l >> 4, cl = l & 15;
  long rowbase = (long)bm * 256 + wm * 64 + rh * 4;
  int colbase = bn * 128 + wn * 64 + cl;
  int seg = bn >> 3;  // block-uniform: 0=Q 1=K 2=V
  const float* bias = (seg == 0) ? bq : (seg == 1) ? bk : bv;
#pragma unroll
  for (int j = 0; j < 4; j++) {
    int c = colbase + j * 16;
    int cl_ = c & 1023;
    float bv_ = bias[cl_];
#pragma unroll
    for (int i = 0; i < 4; i++) {
      long r0 = rowbase + i * 16;
      f32x4 v = acc[i][j];
      if (seg < 2) {
        unsigned short* Ch = (seg == 0) ? Qo : Ko;
#pragma unroll
        for (int t = 0; t < 4; t++)
          Ch[(r0 + t) * (long)E_ + cl_] = f2bu(v[t] + bv_);
      } else {
        ushort4 pk;
        pk.x = f2bu(v[0] + bv_);
        pk.y = f2bu(v[1] + bv_);
        pk.z = f2bu(v[2] + bv_);
        pk.w = f2bu(v[3] + bv_);
        *(ushort4*)(Vt + (long)cl_ * (B_ * S_) + r0) = pk;
      }
    }
  }
}

// ---------------- shared m97-structure GEMM body (scores / PV) ----------------
// MODE 1 (SCORES): P' = exp(s/32) bf16 causal + rowsum atomics into denom.
// MODE 2 (PV): out = acc * 1/denom[row], Keff = (bm+1)*128.
template<int MODE>
__device__ __forceinline__ void gemm_body(
    const unsigned short* __restrict__ A, long sAz, int lda,
    const unsigned short* __restrict__ B, long sBz, int ldb,
    void* __restrict__ C0, long sCz, int ldc, int K, float scale,
    float* __restrict__ denom,
    unsigned short* lA, unsigned short* lB, int bm, int bn, int bz) {
  constexpr int BK = 64;
  const unsigned short* Ab = A + (long)bz * sAz + (long)bm * 128 * lda;
  const unsigned short* Bb = B + (long)bz * sBz + (long)bn * 128 * ldb;
  int Keff = (MODE == 2) ? min(K, (bm + 1) * 128) : K;

  int tid = threadIdx.x;
  int l = tid & 63, w = tid >> 6;
  int wm = w >> 1, wn = w & 1;

  int srow = l >> 3;
  int schunk = (l & 7) * 8;
  const unsigned short* ga[4];
  const unsigned short* gb[4];
  unsigned short* lad[4];
  unsigned short* lbd[4];
#pragma unroll
  for (int i = 0; i < 4; i++) {
    int seg = i * 4 + w;
    int row = seg * 8 + srow;
    ga[i] = Ab + (long)row * lda + schunk;
    gb[i] = Bb + (long)row * ldb + schunk;
    lad[i] = &lA[seg * 512];
    lbd[i] = &lB[seg * 512];
  }
  int aoff[4], boff[4];
#pragma unroll
  for (int i = 0; i < 4; i++) {
    aoff[i] = (wm * 64 + i * 16 + (l & 15)) * BK + (l >> 4) * 8;
    boff[i] = (wn * 64 + i * 16 + (l & 15)) * BK + (l >> 4) * 8;
  }

  f32x4 acc[4][4] = {};

  for (int k0 = 0; k0 < Keff; k0 += BK) {
    __syncthreads();
#pragma unroll
    for (int i = 0; i < 4; i++) {
      gload_lds16(ga[i], lad[i]);
      gload_lds16(gb[i], lbd[i]);
    }
#pragma unroll
    for (int i = 0; i < 4; i++) { ga[i] += BK; gb[i] += BK; }
    __syncthreads();
#pragma unroll
    for (int kk = 0; kk < 2; kk++) {
      short8 af[4], bf[4];
#pragma unroll
      for (int i = 0; i < 4; i++) af[i] = *(const short8*)&lA[aoff[i] + kk * 32];
#pragma unroll
      for (int j = 0; j < 4; j++) bf[j] = *(const short8*)&lB[boff[j] + kk * 32];
#pragma unroll
      for (int i = 0; i < 4; i++)
#pragma unroll
        for (int j = 0; j < 4; j++)
          acc[i][j] = __builtin_amdgcn_mfma_f32_16x16x32_bf16(af[i], bf[j], acc[i][j], 0, 0, 0);
    }
  }

  int rh = l >> 4, cl = l & 15;
  long rowbase = (long)bm * 128 + wm * 64 + rh * 4;
  int colbase = bn * 128 + wn * 64 + cl;

  if constexpr (MODE == 1) {
    // P' = exp(s*scale) masked; j INNERMOST for write-combine (round-7 lesson)
    unsigned short* Ph = (unsigned short*)C0 + (long)bz * sCz;
    float rs[4][4] = {};
#pragma unroll
    for (int i = 0; i < 4; i++) {
      int r0 = (int)rowbase + i * 16;
#pragma unroll
      for (int t = 0; t < 4; t++) {
        int r = r0 + t;
#pragma unroll
        for (int j = 0; j < 4; j++) {
          int c = colbase + j * 16;
          float p = (c <= r) ? __expf(acc[i][j][t] * scale) : 0.f;
          Ph[(long)r * ldc + c] = f2bu(p);
          rs[i][t] += p;
        }
      }
    }
#pragma unroll
    for (int i = 0; i < 4; i++)
#pragma unroll
      for (int t = 0; t < 4; t++) {
        float s = rs[i][t];
        s += __shfl_xor(s, 1);
        s += __shfl_xor(s, 2);
        s += __shfl_xor(s, 4);
        s += __shfl_xor(s, 8);
        rs[i][t] = s;
      }
    if ((l & 15) == 0) {
      float* dz = denom + (long)bz * S_;
#pragma unroll
      for (int i = 0; i < 4; i++)
#pragma unroll
        for (int t = 0; t < 4; t++)
          atomicAdd(&dz[(int)rowbase + i * 16 + t], rs[i][t]);
    }
  } else {
    float* Cf = (float*)C0 + (long)bz * sCz;
    const float* dz = denom + (long)bz * S_;
    float rdn[4][4];
#pragma unroll
    for (int i = 0; i < 4; i++)
#pragma unroll
      for (int t = 0; t < 4; t++)
        rdn[i][t] = 1.0f / dz[(int)rowbase + i * 16 + t];
#pragma unroll
    for (int j = 0; j < 4; j++) {
      int c = colbase + j * 16;
#pragma unroll
      for (int i = 0; i < 4; i++) {
        long r0 = rowbase + i * 16;
        f32x4 v = acc[i][j];
#pragma unroll
        for (int t = 0; t < 4; t++)
          Cf[(r0 + t) * (long)ldc + c] = v[t] * rdn[i][t];
      }
    }
  }
}

// SCORES: lower-tri linear grid (136,1,4); XCD-chunked (136 = 8 x 17).
__global__ __launch_bounds__(256, 3) void k_scores(
    const unsigned short* __restrict__ Q, const unsigned short* __restrict__ K,
    unsigned short* __restrict__ P, float* __restrict__ denom) {
  __shared__ unsigned short lA[128 * 64];
  __shared__ unsigned short lB[128 * 64];
  int t0 = blockIdx.x;
  int t = (t0 & 7) * 17 + (t0 >> 3);
  int bm = (int)((sqrtf(8.f * t + 1.f) - 1.f) * 0.5f);
  while ((bm + 1) * (bm + 2) / 2 <= t) bm++;
  while (bm * (bm + 1) / 2 > t) bm--;
  int bn = t - bm * (bm + 1) / 2;
  gemm_body<1>(Q, (long)S_ * E_, E_, K, (long)S_ * E_, E_,
               P, (long)S_ * S_, S_, E_, 0.03125f, denom,
               lA, lB, bm, bn, blockIdx.z);
}

// PV: grid (8,16,4); bm DESCENDING (longest-first packing).
__global__ __launch_bounds__(256, 3) void k_pv(
    const unsigned short* __restrict__ P, const unsigned short* __restrict__ Vt,
    float* __restrict__ out, const float* __restrict__ denom) {
  __shared__ unsigned short lA[128 * 64];
  __shared__ unsigned short lB[128 * 64];
  int bm = 15 - blockIdx.y;
  gemm_body<2>(P, (long)S_ * S_, S_, Vt, (long)S_, B_ * S_,
               out, (long)S_ * E_, E_, S_, 1.f, (float*)denom,
               lA, lB, bm, blockIdx.x, blockIdx.z);
}

// ---------------- host ----------------
extern "C" void kernel_launch(void* const* d_in, const int* in_sizes, int n_in,
                              void* d_out, int out_size, void* d_ws, size_t ws_size,
                              hipStream_t stream) {
  const float* x  = (const float*)d_in[0];
  const float* Wq = (const float*)d_in[2];
  const float* bq = (const float*)d_in[3];
  const float* Wk = (const float*)d_in[4];
  const float* bk = (const float*)d_in[5];
  const float* Wv = (const float*)d_in[6];
  const float* bv = (const float*)d_in[7];
  float* out = (float*)d_out;

  const long NX = (long)B_ * S_ * E_;  // 8388608
  const long NW = (long)E_ * E_;       // 1048576
  unsigned short* xb  = (unsigned short*)d_ws;
  unsigned short* wqb = xb + NX;       // [3072][1024] contiguous (q,k,v)
  unsigned short* Qb  = wqb + 3 * NW;
  unsigned short* Kb  = Qb + NX;
  unsigned short* Vtb = Kb + NX;       // layout [E][B*S]
  unsigned short* Pb  = Vtb + NX;      // [B][S][S] bf16 unnormalized exp-scores
  float* denom = (float*)(Pb + (long)B_ * S_ * S_);  // [B][S] fp32 row sums

  cvt_f32_bf16<<<8192, 256, 0, stream>>>(x, xb, (int)NX);
  cvt_w3<<<dim3(1024, 1, 3), 256, 0, stream>>>(Wq, Wk, Wv, wqb, (int)NW);
  zden<<<8, 256, 0, stream>>>(denom);

  // fused QKV, 256x128 tile, one residency round (768 blocks @ 3/CU)
  k_qkv<<<dim3(24, 32), 512, 0, stream>>>(xb, wqb, bq, bk, bv, Qb, Kb, Vtb);

  k_scores<<<dim3(136, 1, 4), 256, 0, stream>>>(Qb, Kb, Pb, denom);

  k_pv<<<dim3(8, 16, 4), 256, 0, stream>>>(Pb, Vtb, out, denom);
}

// Round 15
// 162.121 us; speedup vs baseline: 3.5383x; 3.5383x over previous
//
#include <hip/hip_runtime.h>

#define B_ 4
#define S_ 2048
#define E_ 1024

typedef __attribute__((ext_vector_type(8))) short short8;
typedef __attribute__((ext_vector_type(4))) float f32x4;

__device__ __forceinline__ unsigned short f2bu(float f) {
  unsigned u = __builtin_bit_cast(unsigned, f);
  u = (u + 0x7FFFu + ((u >> 16) & 1u)) >> 16;
  return (unsigned short)u;
}

__device__ __forceinline__ void gload_lds16(const void* g, void* l) {
  __builtin_amdgcn_global_load_lds(
      (const __attribute__((address_space(1))) void*)g,
      (__attribute__((address_space(3))) void*)l, 16, 0, 0);
}

// ---------------- merged prologue: x-cvt + W-cvt + denom zero ----------------
// One dispatch replaces three (cvt_f32_bf16, cvt_w3, zden).
// float4 index space: [0, 2097152) -> x; [2097152, 2883584) -> weights;
// tail: 2048 threads each zero a float4 of denom (8192 floats total).
// [Round-14 bug: tail zeroed only 2048 SCALAR floats of the 8192-float
//  denom -> rows 2048+ accumulated across graph replays -> post-timing
//  re-validation failed. Fixed: float4 per tail thread.]
__global__ __launch_bounds__(256) void cvt_all(
    const float* __restrict__ x,
    const float* __restrict__ wq, const float* __restrict__ wk,
    const float* __restrict__ wv,
    unsigned short* __restrict__ xb, unsigned short* __restrict__ wqb,
    float* __restrict__ denom) {
  const long NX4 = 2097152;  // 8388608 / 4
  const long NW4 = 262144;   // 1048576 / 4
  long i = (long)blockIdx.x * 256 + threadIdx.x;
  if (i < NX4) {
    float4 v = ((const float4*)x)[i];
    ushort4 o;
    o.x = f2bu(v.x); o.y = f2bu(v.y); o.z = f2bu(v.z); o.w = f2bu(v.w);
    ((ushort4*)xb)[i] = o;
  } else if (i < NX4 + 3 * NW4) {
    long j = i - NX4;
    int z = (int)(j >> 18);
    long off = j & (NW4 - 1);
    const float* src = (z == 0) ? wq : (z == 1) ? wk : wv;
    float4 v = ((const float4*)src)[off];
    ushort4 o;
    o.x = f2bu(v.x); o.y = f2bu(v.y); o.z = f2bu(v.z); o.w = f2bu(v.w);
    ((ushort4*)(wqb + (long)z * 1048576))[off] = o;
  } else {
    long j = i - NX4 - 3 * NW4;
    if (j < (long)(B_ * S_) / 4)
      ((float4*)denom)[j] = float4{0.f, 0.f, 0.f, 0.f};
  }
}

// ---------------- shared m97-structure GEMM body ----------------
// [round-10 proven config: 128x128 tile, BK=64, 4 waves, 3 blocks/CU]
// MODE 0 (QKV): C = A*W^T+bias routed Q/K rowmajor, V transposed.
// MODE 1 (SCORES): P' = exp(s/32) bf16 causal + rowsum atomics into denom.
// MODE 2 (PV): out = acc * 1/denom[row], Keff = (bm+1)*128.
template<int MODE>
__device__ __forceinline__ void gemm_body(
    const unsigned short* __restrict__ A, long sAz, int lda,
    const unsigned short* __restrict__ B, long sBz, int ldb,
    const float* __restrict__ bias0, const float* __restrict__ bias1,
    const float* __restrict__ bias2,
    void* __restrict__ C0, void* __restrict__ C1, void* __restrict__ C2,
    long sCz, int ldc, int K, float scale, float* __restrict__ denom,
    unsigned short* lA, unsigned short* lB, int bm, int bn, int bz) {
  constexpr int BK = 64;
  const unsigned short* Ab = A + (long)bz * sAz + (long)bm * 128 * lda;
  const unsigned short* Bb = B + (long)bz * sBz + (long)bn * 128 * ldb;
  int Keff = (MODE == 2) ? min(K, (bm + 1) * 128) : K;

  int tid = threadIdx.x;
  int l = tid & 63, w = tid >> 6;
  int wm = w >> 1, wn = w & 1;  // wave computes 64x64 at (wm*64, wn*64)

  int srow = l >> 3;
  int schunk = (l & 7) * 8;
  const unsigned short* ga[4];
  const unsigned short* gb[4];
  unsigned short* lad[4];
  unsigned short* lbd[4];
#pragma unroll
  for (int i = 0; i < 4; i++) {
    int seg = i * 4 + w;
    int row = seg * 8 + srow;
    ga[i] = Ab + (long)row * lda + schunk;
    gb[i] = Bb + (long)row * ldb + schunk;
    lad[i] = &lA[seg * 512];
    lbd[i] = &lB[seg * 512];
  }
  int aoff[4], boff[4];
#pragma unroll
  for (int i = 0; i < 4; i++) {
    aoff[i] = (wm * 64 + i * 16 + (l & 15)) * BK + (l >> 4) * 8;
    boff[i] = (wn * 64 + i * 16 + (l & 15)) * BK + (l >> 4) * 8;
  }

  f32x4 acc[4][4] = {};

  for (int k0 = 0; k0 < Keff; k0 += BK) {
    __syncthreads();
#pragma unroll
    for (int i = 0; i < 4; i++) {
      gload_lds16(ga[i], lad[i]);
      gload_lds16(gb[i], lbd[i]);
    }
#pragma unroll
    for (int i = 0; i < 4; i++) { ga[i] += BK; gb[i] += BK; }
    __syncthreads();
#pragma unroll
    for (int kk = 0; kk < 2; kk++) {
      short8 af[4], bf[4];
#pragma unroll
      for (int i = 0; i < 4; i++) af[i] = *(const short8*)&lA[aoff[i] + kk * 32];
#pragma unroll
      for (int j = 0; j < 4; j++) bf[j] = *(const short8*)&lB[boff[j] + kk * 32];
#pragma unroll
      for (int i = 0; i < 4; i++)
#pragma unroll
        for (int j = 0; j < 4; j++)
          acc[i][j] = __builtin_amdgcn_mfma_f32_16x16x32_bf16(af[i], bf[j], acc[i][j], 0, 0, 0);
    }
  }

  // epilogue: D col = lane&15, row = (lane>>4)*4 + t   [m89-verified]
  int rh = l >> 4, cl = l & 15;
  long rowbase = (long)bm * 128 + wm * 64 + rh * 4;
  int colbase = bn * 128 + wn * 64 + cl;

  if constexpr (MODE == 0) {
    int seg = bn >> 3;  // wave-uniform: 0=Q 1=K 2=V
    const float* bias = (seg == 0) ? bias0 : (seg == 1) ? bias1 : bias2;
#pragma unroll
    for (int j = 0; j < 4; j++) {
      int c = colbase + j * 16;
      int cl_ = c & 1023;
      float bv_ = bias[cl_];
#pragma unroll
      for (int i = 0; i < 4; i++) {
        long r0 = rowbase + i * 16;
        f32x4 v = acc[i][j];
        if (seg < 2) {
          unsigned short* Ch = (unsigned short*)((seg == 0) ? C0 : C1);
#pragma unroll
          for (int t = 0; t < 4; t++)
            Ch[(r0 + t) * (long)E_ + cl_] = f2bu(v[t] + bv_);
        } else {
          unsigned short* Vt = (unsigned short*)C2;
          ushort4 pk;
          pk.x = f2bu(v[0] + bv_);
          pk.y = f2bu(v[1] + bv_);
          pk.z = f2bu(v[2] + bv_);
          pk.w = f2bu(v[3] + bv_);
          *(ushort4*)(Vt + (long)cl_ * (B_ * S_) + r0) = pk;
        }
      }
    }
  } else if constexpr (MODE == 1) {
    // P' = exp(s*scale) masked; j INNERMOST so each lane's 4 stores to a
    // row's 128B span issue back-to-back (write-combine; round-7 lesson).
    unsigned short* Ph = (unsigned short*)C0 + (long)bz * sCz;
    float rs[4][4] = {};
#pragma unroll
    for (int i = 0; i < 4; i++) {
      int r0 = (int)rowbase + i * 16;
#pragma unroll
      for (int t = 0; t < 4; t++) {
        int r = r0 + t;
#pragma unroll
        for (int j = 0; j < 4; j++) {
          int c = colbase + j * 16;
          float p = (c <= r) ? __expf(acc[i][j][t] * scale) : 0.f;
          Ph[(long)r * ldc + c] = f2bu(p);
          rs[i][t] += p;
        }
      }
    }
#pragma unroll
    for (int i = 0; i < 4; i++)
#pragma unroll
      for (int t = 0; t < 4; t++) {
        float s = rs[i][t];
        s += __shfl_xor(s, 1);
        s += __shfl_xor(s, 2);
        s += __shfl_xor(s, 4);
        s += __shfl_xor(s, 8);
        rs[i][t] = s;
      }
    if ((l & 15) == 0) {
      float* dz = denom + (long)bz * S_;
#pragma unroll
      for (int i = 0; i < 4; i++)
#pragma unroll
        for (int t = 0; t < 4; t++)
          atomicAdd(&dz[(int)rowbase + i * 16 + t], rs[i][t]);
    }
  } else {
    float* Cf = (float*)C0 + (long)bz * sCz;
    const float* dz = denom + (long)bz * S_;
    float rdn[4][4];
#pragma unroll
    for (int i = 0; i < 4; i++)
#pragma unroll
      for (int t = 0; t < 4; t++)
        rdn[i][t] = 1.0f / dz[(int)rowbase + i * 16 + t];
#pragma unroll
    for (int j = 0; j < 4; j++) {
      int c = colbase + j * 16;
#pragma unroll
      for (int i = 0; i < 4; i++) {
        long r0 = rowbase + i * 16;
        f32x4 v = acc[i][j];
#pragma unroll
        for (int t = 0; t < 4; t++)
          Cf[(r0 + t) * (long)ldc + c] = v[t] * rdn[i][t];
      }
    }
  }
}

// ---------------- named kernels (round-10 proven configs) ----------------
// QKV: grid (24,64); XCD bm-chunked swizzle (1536 = 8 x 192).
__global__ __launch_bounds__(256, 3) void k_qkv(
    const unsigned short* __restrict__ A, const unsigned short* __restrict__ W,
    const float* __restrict__ bq, const float* __restrict__ bk,
    const float* __restrict__ bv,
    unsigned short* __restrict__ Qo, unsigned short* __restrict__ Ko,
    unsigned short* __restrict__ Vt) {
  __shared__ unsigned short lA[128 * 64];
  __shared__ unsigned short lB[128 * 64];
  int bid = blockIdx.y * 24 + blockIdx.x;
  int nb = (bid & 7) * 192 + (bid >> 3);
  gemm_body<0>(A, 0, E_, W, 0, E_, bq, bk, bv, Qo, Ko, Vt,
               0, E_, E_, 1.f, nullptr, lA, lB, nb / 24, nb % 24, 0);
}

// SCORES: lower-tri linear grid (136,1,4); XCD-chunked (136 = 8 x 17).
__global__ __launch_bounds__(256, 3) void k_scores(
    const unsigned short* __restrict__ Q, const unsigned short* __restrict__ K,
    unsigned short* __restrict__ P, float* __restrict__ denom) {
  __shared__ unsigned short lA[128 * 64];
  __shared__ unsigned short lB[128 * 64];
  int t0 = blockIdx.x;
  int t = (t0 & 7) * 17 + (t0 >> 3);
  int bm = (int)((sqrtf(8.f * t + 1.f) - 1.f) * 0.5f);
  while ((bm + 1) * (bm + 2) / 2 <= t) bm++;
  while (bm * (bm + 1) / 2 > t) bm--;
  int bn = t - bm * (bm + 1) / 2;
  gemm_body<1>(Q, (long)S_ * E_, E_, K, (long)S_ * E_, E_,
               nullptr, nullptr, nullptr, P, nullptr, nullptr,
               (long)S_ * S_, S_, E_, 0.03125f, denom,
               lA, lB, bm, bn, blockIdx.z);
}

// PV: grid (8,16,4); bm DESCENDING (longest-first packing).
__global__ __launch_bounds__(256, 3) void k_pv(
    const unsigned short* __restrict__ P, const unsigned short* __restrict__ Vt,
    float* __restrict__ out, const float* __restrict__ denom) {
  __shared__ unsigned short lA[128 * 64];
  __shared__ unsigned short lB[128 * 64];
  int bm = 15 - blockIdx.y;
  gemm_body<2>(P, (long)S_ * S_, S_, Vt, (long)S_, B_ * S_,
               nullptr, nullptr, nullptr, out, nullptr, nullptr,
               (long)S_ * E_, E_, S_, 1.f, (float*)denom,
               lA, lB, bm, blockIdx.x, blockIdx.z);
}

// ---------------- host ----------------
extern "C" void kernel_launch(void* const* d_in, const int* in_sizes, int n_in,
                              void* d_out, int out_size, void* d_ws, size_t ws_size,
                              hipStream_t stream) {
  const float* x  = (const float*)d_in[0];
  const float* Wq = (const float*)d_in[2];
  const float* bq = (const float*)d_in[3];
  const float* Wk = (const float*)d_in[4];
  const float* bk = (const float*)d_in[5];
  const float* Wv = (const float*)d_in[6];
  const float* bv = (const float*)d_in[7];
  float* out = (float*)d_out;

  const long NX = (long)B_ * S_ * E_;  // 8388608
  const long NW = (long)E_ * E_;       // 1048576
  unsigned short* xb  = (unsigned short*)d_ws;
  unsigned short* wqb = xb + NX;       // [3072][1024] contiguous (q,k,v)
  unsigned short* Qb  = wqb + 3 * NW;
  unsigned short* Kb  = Qb + NX;
  unsigned short* Vtb = Kb + NX;       // layout [E][B*S]
  unsigned short* Pb  = Vtb + NX;      // [B][S][S] bf16 unnormalized exp-scores
  float* denom = (float*)(Pb + (long)B_ * S_ * S_);  // [B][S] fp32 row sums

  // merged prologue: 2097152 + 786432 + 2048 float4 slots -> 11272 blocks
  cvt_all<<<11272, 256, 0, stream>>>(x, Wq, Wk, Wv, xb, wqb, denom);

  k_qkv<<<dim3(24, 64), 256, 0, stream>>>(xb, wqb, bq, bk, bv, Qb, Kb, Vtb);

  k_scores<<<dim3(136, 1, 4), 256, 0, stream>>>(Qb, Kb, Pb, denom);

  k_pv<<<dim3(8, 16, 4), 256, 0, stream>>>(Pb, Vtb, out, denom);
}